// Round 20
// baseline (279.571 us; speedup 1.0000x reference)
//
#include <hip/hip_runtime.h>
#include <cstdint>
#include <cstddef>

#define NH 12
#define HDIM 64
#define C_ 768
#define C3 2304
#define SEQ 1024
#define LS 72     // LDS row stride for relgemm staging (144B)
#define SMAX 6.0f
#define LOG2E 1.4426950408889634f

typedef short bf16x8_t __attribute__((ext_vector_type(8)));
typedef float f32x4_t __attribute__((ext_vector_type(4)));
typedef unsigned short u16x4_t __attribute__((ext_vector_type(4)));

__device__ __forceinline__ unsigned short bf16_rne(float x) {
    unsigned int u = __float_as_uint(x);
    u += 0x7FFFu + ((u >> 16) & 1u);
    return (unsigned short)(u >> 16);
}
__device__ __forceinline__ float bf16f(unsigned short h) {
    return __uint_as_float(((unsigned int)h) << 16);
}

__device__ __forceinline__ void load_lds16(const unsigned short* g, unsigned short* l) {
    auto gp = (const __attribute__((address_space(1))) unsigned short*)(uintptr_t)g;
    auto lp = (__attribute__((address_space(3))) unsigned short*)(uint32_t)(uintptr_t)l;
    __builtin_amdgcn_global_load_lds(gp, lp, 16, 0, 0);
}

__device__ __forceinline__ int swz(int row, int g) {
    const int pr = row >> 1;
    const int ch = (((row & 1) << 2) | g) ^ (pr & 7);
    return pr * 64 + ch * 8;
}

// ---------------- fused prep: x->bf16 | splitT(w_qkv) | splitT(w_proj) | relcat ----------------
__device__ __forceinline__ void splitT_body(const float* __restrict__ W,
                                            unsigned short* __restrict__ Thi,
                                            unsigned short* __restrict__ Tlo,
                                            int Kdim, int Ndim, int kb, int nb,
                                            float (*tile)[33], int t)
{
    const int lr = t >> 3, lc = (t & 7) * 4;
    *(float4*)&tile[lr][lc] = *(const float4*)&W[(size_t)(kb + lr) * Ndim + nb + lc];
    __syncthreads();
    const float v0 = tile[lc + 0][lr];
    const float v1 = tile[lc + 1][lr];
    const float v2 = tile[lc + 2][lr];
    const float v3 = tile[lc + 3][lr];
    u16x4_t h, l;
    h.x = bf16_rne(v0); l.x = bf16_rne(v0 - bf16f(h.x));
    h.y = bf16_rne(v1); l.y = bf16_rne(v1 - bf16f(h.y));
    h.z = bf16_rne(v2); l.z = bf16_rne(v2 - bf16f(h.z));
    h.w = bf16_rne(v3); l.w = bf16_rne(v3 - bf16f(h.w));
    *(u16x4_t*)&Thi[(size_t)(nb + lr) * Kdim + kb + lc] = h;
    *(u16x4_t*)&Tlo[(size_t)(nb + lr) * Kdim + kb + lc] = l;
}

__global__ __launch_bounds__(256)
void prep_kernel(const float* __restrict__ x, const float* __restrict__ w_qkv,
                 const float* __restrict__ w_proj,
                 const float* __restrict__ rel_h, const float* __restrict__ rel_w,
                 unsigned short* __restrict__ xhi,
                 unsigned short* __restrict__ wqh, unsigned short* __restrict__ wql,
                 unsigned short* __restrict__ wph, unsigned short* __restrict__ wpl,
                 unsigned short* __restrict__ relcat)
{
    __shared__ float tile[32][33];
    const int bid = blockIdx.x, tid = threadIdx.x;
    if (bid < 6144) {
        const int i = bid * 256 + tid;
        float4 v = ((const float4*)x)[i];
        u16x4_t h;
        h.x = bf16_rne(v.x); h.y = bf16_rne(v.y); h.z = bf16_rne(v.z); h.w = bf16_rne(v.w);
        ((u16x4_t*)xhi)[i] = h;
    } else if (bid < 7872) {
        const int local = bid - 6144;
        const int bx = local % 72, by = local / 72;
        splitT_body(w_qkv, wqh, wql, C_, C3, by * 32, bx * 32, tile, tid);
    } else if (bid < 8448) {
        const int local = bid - 7872;
        const int bx = local % 24, by = local / 24;
        splitT_body(w_proj, wph, wpl, C_, C_, by * 32, bx * 32, tile, tid);
    } else {
        const int i = (bid - 8448) * 256 + tid;
        if (i < 2016) {
            const int j = i * 4;
            const int row = j >> 6, col = j & 63;
            const float* src = row < 63 ? &rel_h[row * 64 + col] : &rel_w[(row - 63) * 64 + col];
            const float4 v = *(const float4*)src;
            u16x4_t h;
            h.x = bf16_rne(v.x); h.y = bf16_rne(v.y); h.z = bf16_rne(v.z); h.w = bf16_rne(v.w);
            *(u16x4_t*)&relcat[j] = h;
        }
    }
}

// ---------------- QKV GEMM: plain bf16, double-buffered DMA, XCD-affine ----------------
__global__ __launch_bounds__(256, 4)
void qkvgemm_kernel(const unsigned short* __restrict__ Ahi, const unsigned short* __restrict__ BThi,
                    const float* __restrict__ bias,
                    unsigned short* __restrict__ q_hi, unsigned short* __restrict__ k_hi,
                    unsigned short* __restrict__ vT)
{
    constexpr int K = 768;
    __shared__ unsigned short As[2][4096];
    __shared__ unsigned short Bs[2][4096];
    const int tid = threadIdx.x;
    const int w = tid >> 6, lane = tid & 63, g = lane >> 4, r = lane & 15;
    const int wr = (w >> 1) * 64, wc = (w & 1) * 64;

    const int bid  = blockIdx.x;
    const int xcd  = bid & 7;
    const int idx  = bid >> 3;
    const int msub = idx & 7;
    const int ntile = idx >> 3;
    const int m0 = (xcd * 8 + msub) * 128;
    const int n0 = ntile * 128;

    int row_[2], gc_[2];
#pragma unroll
    for (int i = 0; i < 2; ++i) {
        const int s = i * 256 + tid;
        const int pr = s >> 3;
        const int u = (s & 7) ^ (pr & 7);
        row_[i] = pr * 2 + (u >> 2);
        gc_[i]  = u & 3;
    }
    const unsigned short* gA0 = Ahi + (size_t)(m0 + row_[0]) * K + gc_[0] * 8;
    const unsigned short* gA1 = Ahi + (size_t)(m0 + row_[1]) * K + gc_[1] * 8;
    const unsigned short* gB0 = BThi + (size_t)(n0 + row_[0]) * K + gc_[0] * 8;
    const unsigned short* gB1 = BThi + (size_t)(n0 + row_[1]) * K + gc_[1] * 8;
    const int lofs0 = w * 512;
    const int lofs1 = 2048 + w * 512;

    f32x4_t acc[4][4];
#pragma unroll
    for (int i = 0; i < 4; ++i)
#pragma unroll
        for (int j = 0; j < 4; ++j)
#pragma unroll
            for (int q = 0; q < 4; ++q) acc[i][j][q] = 0.f;

    load_lds16(gA0, &As[0][lofs0]);
    load_lds16(gA1, &As[0][lofs1]);
    load_lds16(gB0, &Bs[0][lofs0]);
    load_lds16(gB1, &Bs[0][lofs1]);

    int cur = 0;
    for (int k0 = 0; k0 < K; k0 += 32) {
        __syncthreads();
        if (k0 + 32 < K) {
            const int nb2 = cur ^ 1;
            load_lds16(gA0 + k0 + 32, &As[nb2][lofs0]);
            load_lds16(gA1 + k0 + 32, &As[nb2][lofs1]);
            load_lds16(gB0 + k0 + 32, &Bs[nb2][lofs0]);
            load_lds16(gB1 + k0 + 32, &Bs[nb2][lofs1]);
        }
        bf16x8_t am[4];
#pragma unroll
        for (int i = 0; i < 4; ++i)
            am[i] = *(const bf16x8_t*)&As[cur][swz(wr + 16 * i + r, g)];
        __builtin_amdgcn_s_setprio(1);
#pragma unroll
        for (int j = 0; j < 4; ++j) {
            const bf16x8_t bn = *(const bf16x8_t*)&Bs[cur][swz(wc + 16 * j + r, g)];
#pragma unroll
            for (int i = 0; i < 4; ++i)
                acc[i][j] = __builtin_amdgcn_mfma_f32_16x16x32_bf16(am[i], bn, acc[i][j], 0, 0, 0);
        }
        __builtin_amdgcn_s_setprio(0);
        cur ^= 1;
    }

    const int third = n0 >= 1536 ? 2 : (n0 >= 768 ? 1 : 0);
    if (third == 2) {
#pragma unroll
        for (int j = 0; j < 4; ++j) {
            const int n = n0 + wc + 16 * j + r;
            const float bj = bias[n];
            const int nn = n - 1536;
            const int h = nn >> 6, d = nn & 63;
#pragma unroll
            for (int i = 0; i < 4; ++i) {
                const int m = m0 + wr + 16 * i + 4 * g;
                const int b = m >> 10, t = m & 1023;
                const size_t hb = ((size_t)(b * NH + h)) << 16;
                u16x4_t pv;
#pragma unroll
                for (int q = 0; q < 4; ++q)
                    pv[q] = bf16_rne(acc[i][j][q] + bj);
                *(u16x4_t*)&vT[hb + (size_t)d * 1024 + t] = pv;
            }
        }
    } else {
        unsigned short* outH = third == 1 ? k_hi : q_hi;
#pragma unroll
        for (int j = 0; j < 4; ++j) {
            const int n = n0 + wc + 16 * j + r;
            const float bj = bias[n];
            const int nn = n - third * 768;
            const int h = nn >> 6, d = nn & 63;
#pragma unroll
            for (int i = 0; i < 4; ++i) {
                const int m = m0 + wr + 16 * i + 4 * g;
                const int b = m >> 10, t = m & 1023;
                const size_t hb = ((size_t)(b * NH + h)) << 16;
                unsigned short* dh = outH + hb + (size_t)t * 64 + d;
#pragma unroll
                for (int q = 0; q < 4; ++q)
                    dh[(size_t)q * 64] = bf16_rne(acc[i][j][q] + bj);
            }
        }
    }
}

// ---------------- proj GEMM: bf16x3, double-buffered DMA, XCD-affine ----------------
__global__ __launch_bounds__(256, 2)
void projgemm_kernel(const unsigned short* __restrict__ Ahi, const unsigned short* __restrict__ Alo,
                     const unsigned short* __restrict__ BThi, const unsigned short* __restrict__ BTlo,
                     const float* __restrict__ bias, float* __restrict__ C)
{
    constexpr int K = 768;
    constexpr int N = C_;
    __shared__ unsigned short Ash[2][4096], Asl[2][4096];
    __shared__ unsigned short Bsh[2][4096], Bsl[2][4096];
    const int tid = threadIdx.x;
    const int w = tid >> 6, lane = tid & 63, g = lane >> 4, r = lane & 15;
    const int wr = (w >> 1) * 64, wc = (w & 1) * 64;

    const int bid  = blockIdx.x;
    const int xcd  = bid & 7;
    const int idx  = bid >> 3;
    const int msub = idx & 7;
    const int ntile = idx >> 3;
    const int m0 = (xcd * 8 + msub) * 128;
    const int n0 = ntile * 128;

    int row_[2], gc_[2];
#pragma unroll
    for (int i = 0; i < 2; ++i) {
        const int s = i * 256 + tid;
        const int pr = s >> 3;
        const int u = (s & 7) ^ (pr & 7);
        row_[i] = pr * 2 + (u >> 2);
        gc_[i]  = u & 3;
    }
    const unsigned short* gAh0 = Ahi + (size_t)(m0 + row_[0]) * K + gc_[0] * 8;
    const unsigned short* gAh1 = Ahi + (size_t)(m0 + row_[1]) * K + gc_[1] * 8;
    const unsigned short* gAl0 = Alo + (size_t)(m0 + row_[0]) * K + gc_[0] * 8;
    const unsigned short* gAl1 = Alo + (size_t)(m0 + row_[1]) * K + gc_[1] * 8;
    const unsigned short* gBh0 = BThi + (size_t)(n0 + row_[0]) * K + gc_[0] * 8;
    const unsigned short* gBh1 = BThi + (size_t)(n0 + row_[1]) * K + gc_[1] * 8;
    const unsigned short* gBl0 = BTlo + (size_t)(n0 + row_[0]) * K + gc_[0] * 8;
    const unsigned short* gBl1 = BTlo + (size_t)(n0 + row_[1]) * K + gc_[1] * 8;
    const int lofs0 = w * 512;
    const int lofs1 = 2048 + w * 512;

    f32x4_t acc[4][4];
#pragma unroll
    for (int i = 0; i < 4; ++i)
#pragma unroll
        for (int j = 0; j < 4; ++j)
#pragma unroll
            for (int q = 0; q < 4; ++q) acc[i][j][q] = 0.f;

    load_lds16(gAh0, &Ash[0][lofs0]);
    load_lds16(gAh1, &Ash[0][lofs1]);
    load_lds16(gAl0, &Asl[0][lofs0]);
    load_lds16(gAl1, &Asl[0][lofs1]);
    load_lds16(gBh0, &Bsh[0][lofs0]);
    load_lds16(gBh1, &Bsh[0][lofs1]);
    load_lds16(gBl0, &Bsl[0][lofs0]);
    load_lds16(gBl1, &Bsl[0][lofs1]);

    int cur = 0;
    for (int k0 = 0; k0 < K; k0 += 32) {
        __syncthreads();
        if (k0 + 32 < K) {
            const int nb2 = cur ^ 1;
            load_lds16(gAh0 + k0 + 32, &Ash[nb2][lofs0]);
            load_lds16(gAh1 + k0 + 32, &Ash[nb2][lofs1]);
            load_lds16(gAl0 + k0 + 32, &Asl[nb2][lofs0]);
            load_lds16(gAl1 + k0 + 32, &Asl[nb2][lofs1]);
            load_lds16(gBh0 + k0 + 32, &Bsh[nb2][lofs0]);
            load_lds16(gBh1 + k0 + 32, &Bsh[nb2][lofs1]);
            load_lds16(gBl0 + k0 + 32, &Bsl[nb2][lofs0]);
            load_lds16(gBl1 + k0 + 32, &Bsl[nb2][lofs1]);
        }
        bf16x8_t amh[4], aml[4];
#pragma unroll
        for (int i = 0; i < 4; ++i) {
            const int o = swz(wr + 16 * i + r, g);
            amh[i] = *(const bf16x8_t*)&Ash[cur][o];
            aml[i] = *(const bf16x8_t*)&Asl[cur][o];
        }
        __builtin_amdgcn_s_setprio(1);
#pragma unroll
        for (int j = 0; j < 4; ++j) {
            const int o = swz(wc + 16 * j + r, g);
            const bf16x8_t bnh = *(const bf16x8_t*)&Bsh[cur][o];
            const bf16x8_t bnl = *(const bf16x8_t*)&Bsl[cur][o];
#pragma unroll
            for (int i = 0; i < 4; ++i) {
                acc[i][j] = __builtin_amdgcn_mfma_f32_16x16x32_bf16(amh[i], bnh, acc[i][j], 0, 0, 0);
                acc[i][j] = __builtin_amdgcn_mfma_f32_16x16x32_bf16(amh[i], bnl, acc[i][j], 0, 0, 0);
                acc[i][j] = __builtin_amdgcn_mfma_f32_16x16x32_bf16(aml[i], bnh, acc[i][j], 0, 0, 0);
            }
        }
        __builtin_amdgcn_s_setprio(0);
        cur ^= 1;
    }

#pragma unroll
    for (int j = 0; j < 4; ++j) {
        const float bj = bias[n0 + wc + 16 * j + r];
#pragma unroll
        for (int i = 0; i < 4; ++i) {
            float* Cp = C + (size_t)(m0 + wr + 16 * i + 4 * g) * N + n0 + wc + 16 * j + r;
#pragma unroll
            for (int q = 0; q < 4; ++q)
                Cp[(size_t)q * N] = acc[i][j][q] + bj;
        }
    }
}

// ------------- relgemm -------------
__global__ __launch_bounds__(256, 4)
void relgemm_kernel(const unsigned short* __restrict__ qhi, const unsigned short* __restrict__ relcat,
                    unsigned short* __restrict__ G)
{
    __shared__ unsigned short bs[128 * LS];
    const int tid = threadIdx.x;
    const int sb = blockIdx.x, bh = blockIdx.y;
    const int w = tid >> 6, lane = tid & 63, g = lane >> 4, r = lane & 15;
    const size_t hb = (size_t)bh << 16;

    {
        const int row = tid >> 1, c32 = (tid & 1) * 32;
        if (row < 126) {
#pragma unroll
            for (int e = 0; e < 4; ++e)
                *(bf16x8_t*)&bs[row * LS + c32 + 8 * e] =
                    *(const bf16x8_t*)&relcat[row * 64 + c32 + 8 * e];
        } else {
            const bf16x8_t z = {0,0,0,0,0,0,0,0};
#pragma unroll
            for (int e = 0; e < 4; ++e)
                *(bf16x8_t*)&bs[row * LS + c32 + 8 * e] = z;
        }
    }
    bf16x8_t aq[2][2];
#pragma unroll
    for (int i = 0; i < 2; ++i)
#pragma unroll
        for (int c = 0; c < 2; ++c)
            aq[i][c] = *(const bf16x8_t*)(qhi + hb + (size_t)(sb * 128 + w * 32 + 16 * i + r) * 64 + c * 32 + 8 * g);
    __syncthreads();

    f32x4_t acc[2][8];
#pragma unroll
    for (int i = 0; i < 2; ++i)
#pragma unroll
        for (int fj = 0; fj < 8; ++fj)
#pragma unroll
            for (int q = 0; q < 4; ++q) acc[i][fj][q] = 0.f;

#pragma unroll
    for (int c = 0; c < 2; ++c)
#pragma unroll
        for (int fj = 0; fj < 8; ++fj) {
            const bf16x8_t brel = *(const bf16x8_t*)&bs[(16 * fj + r) * LS + c * 32 + 8 * g];
#pragma unroll
            for (int i = 0; i < 2; ++i)
                acc[i][fj] = __builtin_amdgcn_mfma_f32_16x16x32_bf16(aq[i][c], brel, acc[i][fj], 0, 0, 0);
        }

    unsigned short* Gb = G + (((size_t)bh << 10) + sb * 128 + w * 32) * 128;
#pragma unroll
    for (int i = 0; i < 2; ++i)
#pragma unroll
        for (int reg = 0; reg < 4; ++reg) {
            unsigned short* Gr = Gb + (size_t)(16 * i + 4 * g + reg) * 128 + r;
#pragma unroll
            for (int fj = 0; fj < 8; ++fj)
                Gr[16 * fj] = bf16_rne(acc[i][fj][reg]);
        }
}

// ------------- attention v13: no LDS, K/V fragments direct from L2-resident global -------------
// grid (96 heads, 16 q-blocks): XCD = bh%8 -> each head's 256 KB K/V L2-resident; no barriers.
__global__ __launch_bounds__(256, 4)
void attn13_kernel(const unsigned short* __restrict__ qhi,
                   const unsigned short* __restrict__ khi,
                   const unsigned short* __restrict__ vT,
                   const unsigned short* __restrict__ G,
                   unsigned short* __restrict__ outh, unsigned short* __restrict__ outl)
{
    const int tid  = threadIdx.x;
    const int bh   = blockIdx.x;
    const int s0   = blockIdx.y * 64;
    const int w    = tid >> 6;
    const int lane = tid & 63;
    const int g    = lane >> 4;
    const int r    = lane & 15;
    const size_t hb = (size_t)bh << 16;

    // Q fragment (B-operand)
    bf16x8_t aq[2];
#pragma unroll
    for (int c = 0; c < 2; ++c)
        aq[c] = *(const bf16x8_t*)(qhi + hb + (size_t)(s0 + w * 16 + r) * 64 + c * 32 + 8 * g);

    // bias state
    const unsigned short* Gbh = G + ((size_t)bh << 17);
    const int q    = s0 + w * 16 + r;
    const int qoff = q * 128;
    const int qcb  = (q >> 5) + 31;
    const int iw   = q & 31;
    float bw[4][2];
#pragma unroll
    for (int reg = 0; reg < 4; ++reg)
#pragma unroll
        for (int jh = 0; jh < 2; ++jh)
            bw[reg][jh] = bf16f(Gbh[qoff + 94 + iw - 16 * jh - 4 * g - reg]) * LOG2E;

    f32x4_t oacc[4];
    float lsum[4];
#pragma unroll
    for (int i = 0; i < 4; ++i) {
        lsum[i] = 0.f;
#pragma unroll
        for (int j = 0; j < 4; ++j) oacc[i][j] = 0.f;
    }

    // direct-fragment base pointers (per-lane part; scalar offsets folded per access)
    const unsigned short* Kb = khi + hb + (size_t)r * 64 + 8 * g;      // + t*64 + c*32
    const unsigned short* Vb = vT + hb + (size_t)r * 1024 + 8 * g;     // + fd*16384 + t0 + 32c

    const int addr_a = (((g & 1) << 5) + r) << 2;
    const int addr_b = addr_a + 64;
    const bool lowg = g < 2;

    for (int t0 = 0; t0 < SEQ; t0 += 64) {
        // ---- QK^T: K fragments straight from global (L2-hot) ----
        f32x4_t sacc[4];
#pragma unroll
        for (int fj = 0; fj < 4; ++fj)
#pragma unroll
            for (int j = 0; j < 4; ++j) sacc[fj][j] = 0.f;
#pragma unroll
        for (int c = 0; c < 2; ++c)
#pragma unroll
            for (int fj = 0; fj < 4; ++fj) {
                const bf16x8_t bkh = *(const bf16x8_t*)(Kb + (size_t)(t0 + 16 * fj) * 64 + c * 32);
                sacc[fj] = __builtin_amdgcn_mfma_f32_16x16x32_bf16(bkh, aq[c], sacc[fj], 0, 0, 0);
            }

        // ---- V fragments issued early (latency hides under softmax) ----
        bf16x8_t bv[2][4];
#pragma unroll
        for (int c = 0; c < 2; ++c)
#pragma unroll
            for (int fd = 0; fd < 4; ++fd)
                bv[c][fd] = *(const bf16x8_t*)(Vb + (size_t)fd * 16384 + t0 + 32 * c);

        // ---- logits (base-2) + exp2 + per-lane partial sums ----
        const int kh0 = t0 >> 5;
        const float bh0 = (bf16f(Gbh[qoff + qcb - kh0])     - SMAX) * LOG2E;
        const float bh1 = (bf16f(Gbh[qoff + qcb - kh0 - 1]) - SMAX) * LOG2E;
#pragma unroll
        for (int fj = 0; fj < 4; ++fj)
#pragma unroll
            for (int reg = 0; reg < 4; ++reg) {
                const float s = fmaf(sacc[fj][reg], 0.125f * LOG2E,
                                     ((fj >> 1) ? bh1 : bh0) + bw[reg][fj & 1]);
                const float e = exp2f(s);
                sacc[fj][reg] = e;
                lsum[reg] += e;
            }

        // ---- pack P to bf16 pairs ----
        unsigned int pk01[4], pk23[4];
#pragma unroll
        for (int fj = 0; fj < 4; ++fj) {
            asm("v_cvt_pk_bf16_f32 %0, %1, %2" : "=v"(pk01[fj]) : "v"(sacc[fj][0]), "v"(sacc[fj][1]));
            asm("v_cvt_pk_bf16_f32 %0, %1, %2" : "=v"(pk23[fj]) : "v"(sacc[fj][2]), "v"(sacc[fj][3]));
        }

        // ---- PV: assemble P B-frag via bpermute, MFMA against direct-loaded V^T ----
#pragma unroll
        for (int c = 0; c < 2; ++c) {
            const int a01A = __builtin_amdgcn_ds_bpermute(addr_a, (int)pk01[2 * c]);
            const int a23A = __builtin_amdgcn_ds_bpermute(addr_a, (int)pk23[2 * c]);
            const int b01A = __builtin_amdgcn_ds_bpermute(addr_b, (int)pk01[2 * c]);
            const int b23A = __builtin_amdgcn_ds_bpermute(addr_b, (int)pk23[2 * c]);
            const int a01B = __builtin_amdgcn_ds_bpermute(addr_a, (int)pk01[2 * c + 1]);
            const int a23B = __builtin_amdgcn_ds_bpermute(addr_a, (int)pk23[2 * c + 1]);
            const int b01B = __builtin_amdgcn_ds_bpermute(addr_b, (int)pk01[2 * c + 1]);
            const int b23B = __builtin_amdgcn_ds_bpermute(addr_b, (int)pk23[2 * c + 1]);
            union { int u[4]; bf16x8_t v; } pf;
            pf.u[0] = lowg ? a01A : a01B;
            pf.u[1] = lowg ? a23A : a23B;
            pf.u[2] = lowg ? b01A : b01B;
            pf.u[3] = lowg ? b23A : b23B;
#pragma unroll
            for (int fd = 0; fd < 4; ++fd)
                oacc[fd] = __builtin_amdgcn_mfma_f32_16x16x32_bf16(bv[c][fd], pf.v, oacc[fd], 0, 0, 0);
        }
    }

    // ---- epilogue: one q-row per lane ----
    const int b = bh / NH, h = bh - (bh / NH) * NH;
    float rs = (lsum[0] + lsum[1]) + (lsum[2] + lsum[3]);
    rs += __shfl_xor(rs, 16);
    rs += __shfl_xor(rs, 32);
    const float rinv = 1.f / rs;
    unsigned short* oph = outh + ((size_t)b * SEQ + q) * C_ + h * HDIM + 4 * g;
    unsigned short* opl = outl + ((size_t)b * SEQ + q) * C_ + h * HDIM + 4 * g;
#pragma unroll
    for (int fd = 0; fd < 4; ++fd) {
        u16x4_t hv, lv;
#pragma unroll
        for (int reg = 0; reg < 4; ++reg) {
            const float v = oacc[fd][reg] * rinv;
            const unsigned short hh = bf16_rne(v);
            hv[reg] = hh;
            lv[reg] = bf16_rne(v - bf16f(hh));
        }
        *(u16x4_t*)(oph + 16 * fd) = hv;
        *(u16x4_t*)(opl + 16 * fd) = lv;
    }
}

extern "C" void kernel_launch(void* const* d_in, const int* in_sizes, int n_in,
                              void* d_out, int out_size, void* d_ws, size_t ws_size,
                              hipStream_t stream) {
    (void)in_sizes; (void)n_in; (void)out_size; (void)ws_size;
    const float* x      = (const float*)d_in[0];
    const float* w_qkv  = (const float*)d_in[1];
    const float* b_qkv  = (const float*)d_in[2];
    const float* w_proj = (const float*)d_in[3];
    const float* b_proj = (const float*)d_in[4];
    const float* rel_h  = (const float*)d_in[5];
    const float* rel_w  = (const float*)d_in[6];
    float* out = (float*)d_out;

    char* base = (char*)d_ws;
    unsigned short* xhi    = (unsigned short*)(base + 0);
    unsigned short* xlo    = (unsigned short*)(base + 12582912);
    unsigned short* wqh    = (unsigned short*)(base + 25165824);
    unsigned short* wql    = (unsigned short*)(base + 28704768);
    unsigned short* wph    = (unsigned short*)(base + 32243712);
    unsigned short* wpl    = (unsigned short*)(base + 33423360);
    unsigned short* qhi    = (unsigned short*)(base + 34603008);
    unsigned short* relcat = (unsigned short*)(base + 47185920);
    unsigned short* khi    = (unsigned short*)(base + 59768832);
    unsigned short* vT     = (unsigned short*)(base + 84934656);
    unsigned short* G      = (unsigned short*)(base + 110100480);
    unsigned short* ohif   = xhi;
    unsigned short* olo    = xlo;

    // 1. fused prep
    prep_kernel<<<8456, 256, 0, stream>>>(x, w_qkv, w_proj, rel_h, rel_w,
                                          xhi, wqh, wql, wph, wpl, relcat);
    // 2. QKV GEMM (q/k row-major, V transposed)
    qkvgemm_kernel<<<1152, 256, 0, stream>>>(xhi, wqh, b_qkv, qhi, khi, vT);
    // 3. G = q @ relcat^T
    {
        dim3 grid(8, 96);
        relgemm_kernel<<<grid, 256, 0, stream>>>(qhi, relcat, G);
    }
    // 4. attention (LDS-free, direct L2 fragment reads)
    {
        dim3 grid(96, SEQ / 64);
        attn13_kernel<<<grid, 256, 0, stream>>>(qhi, khi, vT, G, ohif, olo);
    }
    // 5. proj GEMM
    projgemm_kernel<<<384, 256, 0, stream>>>(ohif, olo, wph, wpl, b_proj, out);
}

// Round 21
// 161.800 us; speedup vs baseline: 1.7279x; 1.7279x over previous
//
#include <hip/hip_runtime.h>
#include <cstdint>
#include <cstddef>

#define NH 12
#define HDIM 64
#define C_ 768
#define C3 2304
#define SEQ 1024
#define LS 72     // K LDS row stride in bf16 elems (144B)
#define LSV 76    // V LDS row stride (152B: conflict-free PV fragment reads)
#define SMAX 6.0f
#define LOG2E 1.4426950408889634f

typedef short bf16x8_t __attribute__((ext_vector_type(8)));
typedef float f32x4_t __attribute__((ext_vector_type(4)));
typedef unsigned short u16x4_t __attribute__((ext_vector_type(4)));

__device__ __forceinline__ unsigned short bf16_rne(float x) {
    unsigned int u = __float_as_uint(x);
    u += 0x7FFFu + ((u >> 16) & 1u);
    return (unsigned short)(u >> 16);
}
__device__ __forceinline__ float bf16f(unsigned short h) {
    return __uint_as_float(((unsigned int)h) << 16);
}

__device__ __forceinline__ void load_lds16(const unsigned short* g, unsigned short* l) {
    auto gp = (const __attribute__((address_space(1))) unsigned short*)(uintptr_t)g;
    auto lp = (__attribute__((address_space(3))) unsigned short*)(uint32_t)(uintptr_t)l;
    __builtin_amdgcn_global_load_lds(gp, lp, 16, 0, 0);
}

__device__ __forceinline__ int swz(int row, int g) {
    const int pr = row >> 1;
    const int ch = (((row & 1) << 2) | g) ^ (pr & 7);
    return pr * 64 + ch * 8;
}

// ---------------- fused prep: x->bf16 | splitT(w_qkv) | splitT(w_proj) | relcat ----------------
__device__ __forceinline__ void splitT_body(const float* __restrict__ W,
                                            unsigned short* __restrict__ Thi,
                                            unsigned short* __restrict__ Tlo,
                                            int Kdim, int Ndim, int kb, int nb,
                                            float (*tile)[33], int t)
{
    const int lr = t >> 3, lc = (t & 7) * 4;
    *(float4*)&tile[lr][lc] = *(const float4*)&W[(size_t)(kb + lr) * Ndim + nb + lc];
    __syncthreads();
    const float v0 = tile[lc + 0][lr];
    const float v1 = tile[lc + 1][lr];
    const float v2 = tile[lc + 2][lr];
    const float v3 = tile[lc + 3][lr];
    u16x4_t h, l;
    h.x = bf16_rne(v0); l.x = bf16_rne(v0 - bf16f(h.x));
    h.y = bf16_rne(v1); l.y = bf16_rne(v1 - bf16f(h.y));
    h.z = bf16_rne(v2); l.z = bf16_rne(v2 - bf16f(h.z));
    h.w = bf16_rne(v3); l.w = bf16_rne(v3 - bf16f(h.w));
    *(u16x4_t*)&Thi[(size_t)(nb + lr) * Kdim + kb + lc] = h;
    *(u16x4_t*)&Tlo[(size_t)(nb + lr) * Kdim + kb + lc] = l;
}

__global__ __launch_bounds__(256)
void prep_kernel(const float* __restrict__ x, const float* __restrict__ w_qkv,
                 const float* __restrict__ w_proj,
                 const float* __restrict__ rel_h, const float* __restrict__ rel_w,
                 unsigned short* __restrict__ xhi,
                 unsigned short* __restrict__ wqh, unsigned short* __restrict__ wql,
                 unsigned short* __restrict__ wph, unsigned short* __restrict__ wpl,
                 unsigned short* __restrict__ relcat)
{
    __shared__ float tile[32][33];
    const int bid = blockIdx.x, tid = threadIdx.x;
    if (bid < 6144) {
        const int i = bid * 256 + tid;
        float4 v = ((const float4*)x)[i];
        u16x4_t h;
        h.x = bf16_rne(v.x); h.y = bf16_rne(v.y); h.z = bf16_rne(v.z); h.w = bf16_rne(v.w);
        ((u16x4_t*)xhi)[i] = h;
    } else if (bid < 7872) {
        const int local = bid - 6144;
        const int bx = local % 72, by = local / 72;
        splitT_body(w_qkv, wqh, wql, C_, C3, by * 32, bx * 32, tile, tid);
    } else if (bid < 8448) {
        const int local = bid - 7872;
        const int bx = local % 24, by = local / 24;
        splitT_body(w_proj, wph, wpl, C_, C_, by * 32, bx * 32, tile, tid);
    } else {
        const int i = (bid - 8448) * 256 + tid;
        if (i < 2016) {
            const int j = i * 4;
            const int row = j >> 6, col = j & 63;
            const float* src = row < 63 ? &rel_h[row * 64 + col] : &rel_w[(row - 63) * 64 + col];
            const float4 v = *(const float4*)src;
            u16x4_t h;
            h.x = bf16_rne(v.x); h.y = bf16_rne(v.y); h.z = bf16_rne(v.z); h.w = bf16_rne(v.w);
            *(u16x4_t*)&relcat[j] = h;
        }
    }
}

// ---------------- QKV GEMM: plain bf16, double-buffered DMA, XCD-affine ----------------
// q/k written [bh][t][64]; V written TRANSPOSED [bh][d][1024].
__global__ __launch_bounds__(256, 4)
void qkvgemm_kernel(const unsigned short* __restrict__ Ahi, const unsigned short* __restrict__ BThi,
                    const float* __restrict__ bias,
                    unsigned short* __restrict__ q_hi, unsigned short* __restrict__ k_hi,
                    unsigned short* __restrict__ vT)
{
    constexpr int K = 768;
    __shared__ unsigned short As[2][4096];
    __shared__ unsigned short Bs[2][4096];
    const int tid = threadIdx.x;
    const int w = tid >> 6, lane = tid & 63, g = lane >> 4, r = lane & 15;
    const int wr = (w >> 1) * 64, wc = (w & 1) * 64;

    const int bid  = blockIdx.x;
    const int xcd  = bid & 7;
    const int idx  = bid >> 3;
    const int msub = idx & 7;
    const int ntile = idx >> 3;
    const int m0 = (xcd * 8 + msub) * 128;
    const int n0 = ntile * 128;

    int row_[2], gc_[2];
#pragma unroll
    for (int i = 0; i < 2; ++i) {
        const int s = i * 256 + tid;
        const int pr = s >> 3;
        const int u = (s & 7) ^ (pr & 7);
        row_[i] = pr * 2 + (u >> 2);
        gc_[i]  = u & 3;
    }
    const unsigned short* gA0 = Ahi + (size_t)(m0 + row_[0]) * K + gc_[0] * 8;
    const unsigned short* gA1 = Ahi + (size_t)(m0 + row_[1]) * K + gc_[1] * 8;
    const unsigned short* gB0 = BThi + (size_t)(n0 + row_[0]) * K + gc_[0] * 8;
    const unsigned short* gB1 = BThi + (size_t)(n0 + row_[1]) * K + gc_[1] * 8;
    const int lofs0 = w * 512;
    const int lofs1 = 2048 + w * 512;

    f32x4_t acc[4][4];
#pragma unroll
    for (int i = 0; i < 4; ++i)
#pragma unroll
        for (int j = 0; j < 4; ++j)
#pragma unroll
            for (int q = 0; q < 4; ++q) acc[i][j][q] = 0.f;

    load_lds16(gA0, &As[0][lofs0]);
    load_lds16(gA1, &As[0][lofs1]);
    load_lds16(gB0, &Bs[0][lofs0]);
    load_lds16(gB1, &Bs[0][lofs1]);

    int cur = 0;
    for (int k0 = 0; k0 < K; k0 += 32) {
        __syncthreads();
        if (k0 + 32 < K) {
            const int nb2 = cur ^ 1;
            load_lds16(gA0 + k0 + 32, &As[nb2][lofs0]);
            load_lds16(gA1 + k0 + 32, &As[nb2][lofs1]);
            load_lds16(gB0 + k0 + 32, &Bs[nb2][lofs0]);
            load_lds16(gB1 + k0 + 32, &Bs[nb2][lofs1]);
        }
        bf16x8_t am[4];
#pragma unroll
        for (int i = 0; i < 4; ++i)
            am[i] = *(const bf16x8_t*)&As[cur][swz(wr + 16 * i + r, g)];
        __builtin_amdgcn_s_setprio(1);
#pragma unroll
        for (int j = 0; j < 4; ++j) {
            const bf16x8_t bn = *(const bf16x8_t*)&Bs[cur][swz(wc + 16 * j + r, g)];
#pragma unroll
            for (int i = 0; i < 4; ++i)
                acc[i][j] = __builtin_amdgcn_mfma_f32_16x16x32_bf16(am[i], bn, acc[i][j], 0, 0, 0);
        }
        __builtin_amdgcn_s_setprio(0);
        cur ^= 1;
    }

    const int third = n0 >= 1536 ? 2 : (n0 >= 768 ? 1 : 0);
    if (third == 2) {
#pragma unroll
        for (int j = 0; j < 4; ++j) {
            const int n = n0 + wc + 16 * j + r;
            const float bj = bias[n];
            const int nn = n - 1536;
            const int h = nn >> 6, d = nn & 63;
#pragma unroll
            for (int i = 0; i < 4; ++i) {
                const int m = m0 + wr + 16 * i + 4 * g;
                const int b = m >> 10, t = m & 1023;
                const size_t hb = ((size_t)(b * NH + h)) << 16;
                u16x4_t pv;
#pragma unroll
                for (int q = 0; q < 4; ++q)
                    pv[q] = bf16_rne(acc[i][j][q] + bj);
                *(u16x4_t*)&vT[hb + (size_t)d * 1024 + t] = pv;
            }
        }
    } else {
        unsigned short* outH = third == 1 ? k_hi : q_hi;
#pragma unroll
        for (int j = 0; j < 4; ++j) {
            const int n = n0 + wc + 16 * j + r;
            const float bj = bias[n];
            const int nn = n - third * 768;
            const int h = nn >> 6, d = nn & 63;
#pragma unroll
            for (int i = 0; i < 4; ++i) {
                const int m = m0 + wr + 16 * i + 4 * g;
                const int b = m >> 10, t = m & 1023;
                const size_t hb = ((size_t)(b * NH + h)) << 16;
                unsigned short* dh = outH + hb + (size_t)t * 64 + d;
#pragma unroll
                for (int q = 0; q < 4; ++q)
                    dh[(size_t)q * 64] = bf16_rne(acc[i][j][q] + bj);
            }
        }
    }
}

// ---------------- proj GEMM: bf16x3, double-buffered DMA, XCD-affine ----------------
__global__ __launch_bounds__(256, 2)
void projgemm_kernel(const unsigned short* __restrict__ Ahi, const unsigned short* __restrict__ Alo,
                     const unsigned short* __restrict__ BThi, const unsigned short* __restrict__ BTlo,
                     const float* __restrict__ bias, float* __restrict__ C)
{
    constexpr int K = 768;
    constexpr int N = C_;
    __shared__ unsigned short Ash[2][4096], Asl[2][4096];
    __shared__ unsigned short Bsh[2][4096], Bsl[2][4096];
    const int tid = threadIdx.x;
    const int w = tid >> 6, lane = tid & 63, g = lane >> 4, r = lane & 15;
    const int wr = (w >> 1) * 64, wc = (w & 1) * 64;

    const int bid  = blockIdx.x;
    const int xcd  = bid & 7;
    const int idx  = bid >> 3;
    const int msub = idx & 7;
    const int ntile = idx >> 3;
    const int m0 = (xcd * 8 + msub) * 128;
    const int n0 = ntile * 128;

    int row_[2], gc_[2];
#pragma unroll
    for (int i = 0; i < 2; ++i) {
        const int s = i * 256 + tid;
        const int pr = s >> 3;
        const int u = (s & 7) ^ (pr & 7);
        row_[i] = pr * 2 + (u >> 2);
        gc_[i]  = u & 3;
    }
    const unsigned short* gAh0 = Ahi + (size_t)(m0 + row_[0]) * K + gc_[0] * 8;
    const unsigned short* gAh1 = Ahi + (size_t)(m0 + row_[1]) * K + gc_[1] * 8;
    const unsigned short* gAl0 = Alo + (size_t)(m0 + row_[0]) * K + gc_[0] * 8;
    const unsigned short* gAl1 = Alo + (size_t)(m0 + row_[1]) * K + gc_[1] * 8;
    const unsigned short* gBh0 = BThi + (size_t)(n0 + row_[0]) * K + gc_[0] * 8;
    const unsigned short* gBh1 = BThi + (size_t)(n0 + row_[1]) * K + gc_[1] * 8;
    const unsigned short* gBl0 = BTlo + (size_t)(n0 + row_[0]) * K + gc_[0] * 8;
    const unsigned short* gBl1 = BTlo + (size_t)(n0 + row_[1]) * K + gc_[1] * 8;
    const int lofs0 = w * 512;
    const int lofs1 = 2048 + w * 512;

    f32x4_t acc[4][4];
#pragma unroll
    for (int i = 0; i < 4; ++i)
#pragma unroll
        for (int j = 0; j < 4; ++j)
#pragma unroll
            for (int q = 0; q < 4; ++q) acc[i][j][q] = 0.f;

    load_lds16(gAh0, &Ash[0][lofs0]);
    load_lds16(gAh1, &Ash[0][lofs1]);
    load_lds16(gAl0, &Asl[0][lofs0]);
    load_lds16(gAl1, &Asl[0][lofs1]);
    load_lds16(gBh0, &Bsh[0][lofs0]);
    load_lds16(gBh1, &Bsh[0][lofs1]);
    load_lds16(gBl0, &Bsl[0][lofs0]);
    load_lds16(gBl1, &Bsl[0][lofs1]);

    int cur = 0;
    for (int k0 = 0; k0 < K; k0 += 32) {
        __syncthreads();
        if (k0 + 32 < K) {
            const int nb2 = cur ^ 1;
            load_lds16(gAh0 + k0 + 32, &Ash[nb2][lofs0]);
            load_lds16(gAh1 + k0 + 32, &Ash[nb2][lofs1]);
            load_lds16(gAl0 + k0 + 32, &Asl[nb2][lofs0]);
            load_lds16(gAl1 + k0 + 32, &Asl[nb2][lofs1]);
            load_lds16(gBh0 + k0 + 32, &Bsh[nb2][lofs0]);
            load_lds16(gBh1 + k0 + 32, &Bsh[nb2][lofs1]);
            load_lds16(gBl0 + k0 + 32, &Bsl[nb2][lofs0]);
            load_lds16(gBl1 + k0 + 32, &Bsl[nb2][lofs1]);
        }
        bf16x8_t amh[4], aml[4];
#pragma unroll
        for (int i = 0; i < 4; ++i) {
            const int o = swz(wr + 16 * i + r, g);
            amh[i] = *(const bf16x8_t*)&Ash[cur][o];
            aml[i] = *(const bf16x8_t*)&Asl[cur][o];
        }
        __builtin_amdgcn_s_setprio(1);
#pragma unroll
        for (int j = 0; j < 4; ++j) {
            const int o = swz(wc + 16 * j + r, g);
            const bf16x8_t bnh = *(const bf16x8_t*)&Bsh[cur][o];
            const bf16x8_t bnl = *(const bf16x8_t*)&Bsl[cur][o];
#pragma unroll
            for (int i = 0; i < 4; ++i) {
                acc[i][j] = __builtin_amdgcn_mfma_f32_16x16x32_bf16(amh[i], bnh, acc[i][j], 0, 0, 0);
                acc[i][j] = __builtin_amdgcn_mfma_f32_16x16x32_bf16(amh[i], bnl, acc[i][j], 0, 0, 0);
                acc[i][j] = __builtin_amdgcn_mfma_f32_16x16x32_bf16(aml[i], bnh, acc[i][j], 0, 0, 0);
            }
        }
        __builtin_amdgcn_s_setprio(0);
        cur ^= 1;
    }

#pragma unroll
    for (int j = 0; j < 4; ++j) {
        const float bj = bias[n0 + wc + 16 * j + r];
#pragma unroll
        for (int i = 0; i < 4; ++i) {
            float* Cp = C + (size_t)(m0 + wr + 16 * i + 4 * g) * N + n0 + wc + 16 * j + r;
#pragma unroll
            for (int q = 0; q < 4; ++q)
                Cp[(size_t)q * N] = acc[i][j][q] + bj;
        }
    }
}

// ------------- relgemm -------------
__global__ __launch_bounds__(256, 4)
void relgemm_kernel(const unsigned short* __restrict__ qhi, const unsigned short* __restrict__ relcat,
                    unsigned short* __restrict__ G)
{
    __shared__ unsigned short bs[128 * LS];
    const int tid = threadIdx.x;
    const int sb = blockIdx.x, bh = blockIdx.y;
    const int w = tid >> 6, lane = tid & 63, g = lane >> 4, r = lane & 15;
    const size_t hb = (size_t)bh << 16;

    {
        const int row = tid >> 1, c32 = (tid & 1) * 32;
        if (row < 126) {
#pragma unroll
            for (int e = 0; e < 4; ++e)
                *(bf16x8_t*)&bs[row * LS + c32 + 8 * e] =
                    *(const bf16x8_t*)&relcat[row * 64 + c32 + 8 * e];
        } else {
            const bf16x8_t z = {0,0,0,0,0,0,0,0};
#pragma unroll
            for (int e = 0; e < 4; ++e)
                *(bf16x8_t*)&bs[row * LS + c32 + 8 * e] = z;
        }
    }
    bf16x8_t aq[2][2];
#pragma unroll
    for (int i = 0; i < 2; ++i)
#pragma unroll
        for (int c = 0; c < 2; ++c)
            aq[i][c] = *(const bf16x8_t*)(qhi + hb + (size_t)(sb * 128 + w * 32 + 16 * i + r) * 64 + c * 32 + 8 * g);
    __syncthreads();

    f32x4_t acc[2][8];
#pragma unroll
    for (int i = 0; i < 2; ++i)
#pragma unroll
        for (int fj = 0; fj < 8; ++fj)
#pragma unroll
            for (int q = 0; q < 4; ++q) acc[i][fj][q] = 0.f;

#pragma unroll
    for (int c = 0; c < 2; ++c)
#pragma unroll
        for (int fj = 0; fj < 8; ++fj) {
            const bf16x8_t brel = *(const bf16x8_t*)&bs[(16 * fj + r) * LS + c * 32 + 8 * g];
#pragma unroll
            for (int i = 0; i < 2; ++i)
                acc[i][fj] = __builtin_amdgcn_mfma_f32_16x16x32_bf16(aq[i][c], brel, acc[i][fj], 0, 0, 0);
        }

    unsigned short* Gb = G + (((size_t)bh << 10) + sb * 128 + w * 32) * 128;
#pragma unroll
    for (int i = 0; i < 2; ++i)
#pragma unroll
        for (int reg = 0; reg < 4; ++reg) {
            unsigned short* Gr = Gb + (size_t)(16 * i + 4 * g + reg) * 128 + r;
#pragma unroll
            for (int fj = 0; fj < 8; ++fj)
                Gr[16 * fj] = bf16_rne(acc[i][fj][reg]);
        }
}

// ------------- attention v12: swapped operands, P in registers, pre-transposed V -------------
__global__ __launch_bounds__(256, 4)
void attn12_kernel(const unsigned short* __restrict__ qhi,
                   const unsigned short* __restrict__ khi,
                   const unsigned short* __restrict__ vT,
                   const unsigned short* __restrict__ G,
                   unsigned short* __restrict__ outh, unsigned short* __restrict__ outl)
{
    __shared__ unsigned short ksh[2 * 64 * LS];
    __shared__ unsigned short vsh[2 * 64 * LSV];

    const int tid  = threadIdx.x;
    const int bh   = blockIdx.x;
    const int s0   = blockIdx.y * 64;
    const int w    = tid >> 6;
    const int lane = tid & 63;
    const int g    = lane >> 4;
    const int r    = lane & 15;
    const size_t hb = (size_t)bh << 16;

    bf16x8_t aq[2];
#pragma unroll
    for (int c = 0; c < 2; ++c)
        aq[c] = *(const bf16x8_t*)(qhi + hb + (size_t)(s0 + w * 16 + r) * 64 + c * 32 + 8 * g);

    const unsigned short* Gbh = G + ((size_t)bh << 17);
    const int q    = s0 + w * 16 + r;
    const int qoff = q * 128;
    const int qcb  = (q >> 5) + 31;
    const int iw   = q & 31;
    float bw[4][2];
#pragma unroll
    for (int reg = 0; reg < 4; ++reg)
#pragma unroll
        for (int jh = 0; jh < 2; ++jh)
            bw[reg][jh] = bf16f(Gbh[qoff + 94 + iw - 16 * jh - 4 * g - reg]) * LOG2E;

    f32x4_t oacc[4];
    float lsum[4];
#pragma unroll
    for (int i = 0; i < 4; ++i) {
        lsum[i] = 0.f;
#pragma unroll
        for (int j = 0; j < 4; ++j) oacc[i][j] = 0.f;
    }

    const int krow = tid >> 2, kc16 = (tid & 3) * 16;   // K staging map
    const int vd = tid >> 3, vt = (tid & 7) * 8;        // V staging map (rows vd, vd+32)
    const int addr_a = (((g & 1) << 5) + r) << 2;
    const int addr_b = addr_a + 64;
    const bool lowg = g < 2;

    {
        const unsigned short* kh = khi + hb + (size_t)krow * 64 + kc16;
        const bf16x8_t a0 = *(const bf16x8_t*)kh;
        const bf16x8_t a1 = *(const bf16x8_t*)(kh + 8);
        const bf16x8_t va = *(const bf16x8_t*)(vT + hb + (size_t)vd * 1024 + vt);
        const bf16x8_t vb = *(const bf16x8_t*)(vT + hb + (size_t)(vd + 32) * 1024 + vt);
        *(bf16x8_t*)&ksh[krow * LS + kc16]     = a0;
        *(bf16x8_t*)&ksh[krow * LS + kc16 + 8] = a1;
        *(bf16x8_t*)&vsh[vd * LSV + vt]        = va;
        *(bf16x8_t*)&vsh[(vd + 32) * LSV + vt] = vb;
    }
    __syncthreads();

    int cur = 0;
    for (int t0 = 0; t0 < SEQ; t0 += 64) {
        const int cok = cur * 64 * LS;
        const int cov = cur * 64 * LSV;
        const int tn = (t0 + 64 < SEQ) ? t0 + 64 : t0;
        bf16x8_t nk0, nk1, nva, nvb;
        {
            const unsigned short* kh = khi + hb + (size_t)(tn + krow) * 64 + kc16;
            nk0 = *(const bf16x8_t*)kh;
            nk1 = *(const bf16x8_t*)(kh + 8);
            nva = *(const bf16x8_t*)(vT + hb + (size_t)vd * 1024 + tn + vt);
            nvb = *(const bf16x8_t*)(vT + hb + (size_t)(vd + 32) * 1024 + tn + vt);
        }

        f32x4_t sacc[4];
#pragma unroll
        for (int fj = 0; fj < 4; ++fj)
#pragma unroll
            for (int j = 0; j < 4; ++j) sacc[fj][j] = 0.f;
#pragma unroll
        for (int c = 0; c < 2; ++c)
#pragma unroll
            for (int fj = 0; fj < 4; ++fj) {
                const bf16x8_t bkh = *(const bf16x8_t*)&ksh[cok + (16 * fj + r) * LS + c * 32 + 8 * g];
                sacc[fj] = __builtin_amdgcn_mfma_f32_16x16x32_bf16(bkh, aq[c], sacc[fj], 0, 0, 0);
            }

        const int kh0 = t0 >> 5;
        const float bh0 = (bf16f(Gbh[qoff + qcb - kh0])     - SMAX) * LOG2E;
        const float bh1 = (bf16f(Gbh[qoff + qcb - kh0 - 1]) - SMAX) * LOG2E;
#pragma unroll
        for (int fj = 0; fj < 4; ++fj)
#pragma unroll
            for (int reg = 0; reg < 4; ++reg) {
                const float s = fmaf(sacc[fj][reg], 0.125f * LOG2E,
                                     ((fj >> 1) ? bh1 : bh0) + bw[reg][fj & 1]);
                const float e = exp2f(s);
                sacc[fj][reg] = e;
                lsum[reg] += e;
            }

        unsigned int pk01[4], pk23[4];
#pragma unroll
        for (int fj = 0; fj < 4; ++fj) {
            asm("v_cvt_pk_bf16_f32 %0, %1, %2" : "=v"(pk01[fj]) : "v"(sacc[fj][0]), "v"(sacc[fj][1]));
            asm("v_cvt_pk_bf16_f32 %0, %1, %2" : "=v"(pk23[fj]) : "v"(sacc[fj][2]), "v"(sacc[fj][3]));
        }

#pragma unroll
        for (int c = 0; c < 2; ++c) {
            const int a01A = __builtin_amdgcn_ds_bpermute(addr_a, (int)pk01[2 * c]);
            const int a23A = __builtin_amdgcn_ds_bpermute(addr_a, (int)pk23[2 * c]);
            const int b01A = __builtin_amdgcn_ds_bpermute(addr_b, (int)pk01[2 * c]);
            const int b23A = __builtin_amdgcn_ds_bpermute(addr_b, (int)pk23[2 * c]);
            const int a01B = __builtin_amdgcn_ds_bpermute(addr_a, (int)pk01[2 * c + 1]);
            const int a23B = __builtin_amdgcn_ds_bpermute(addr_a, (int)pk23[2 * c + 1]);
            const int b01B = __builtin_amdgcn_ds_bpermute(addr_b, (int)pk01[2 * c + 1]);
            const int b23B = __builtin_amdgcn_ds_bpermute(addr_b, (int)pk23[2 * c + 1]);
            union { int u[4]; bf16x8_t v; } pf;
            pf.u[0] = lowg ? a01A : a01B;
            pf.u[1] = lowg ? a23A : a23B;
            pf.u[2] = lowg ? b01A : b01B;
            pf.u[3] = lowg ? b23A : b23B;
#pragma unroll
            for (int fd = 0; fd < 4; ++fd) {
                const bf16x8_t bvh = *(const bf16x8_t*)&vsh[cov + (16 * fd + r) * LSV + c * 32 + 8 * g];
                oacc[fd] = __builtin_amdgcn_mfma_f32_16x16x32_bf16(bvh, pf.v, oacc[fd], 0, 0, 0);
            }
        }

        const int nok = (cur ^ 1) * 64 * LS;
        const int nov = (cur ^ 1) * 64 * LSV;
        *(bf16x8_t*)&ksh[nok + krow * LS + kc16]      = nk0;
        *(bf16x8_t*)&ksh[nok + krow * LS + kc16 + 8]  = nk1;
        *(bf16x8_t*)&vsh[nov + vd * LSV + vt]         = nva;
        *(bf16x8_t*)&vsh[nov + (vd + 32) * LSV + vt]  = nvb;
        __syncthreads();
        cur ^= 1;
    }

    const int b = bh / NH, h = bh - (bh / NH) * NH;
    float rs = (lsum[0] + lsum[1]) + (lsum[2] + lsum[3]);
    rs += __shfl_xor(rs, 16);
    rs += __shfl_xor(rs, 32);
    const float rinv = 1.f / rs;
    unsigned short* oph = outh + ((size_t)b * SEQ + q) * C_ + h * HDIM + 4 * g;
    unsigned short* opl = outl + ((size_t)b * SEQ + q) * C_ + h * HDIM + 4 * g;
#pragma unroll
    for (int fd = 0; fd < 4; ++fd) {
        u16x4_t hv, lv;
#pragma unroll
        for (int reg = 0; reg < 4; ++reg) {
            const float v = oacc[fd][reg] * rinv;
            const unsigned short hh = bf16_rne(v);
            hv[reg] = hh;
            lv[reg] = bf16_rne(v - bf16f(hh));
        }
        *(u16x4_t*)(oph + 16 * fd) = hv;
        *(u16x4_t*)(opl + 16 * fd) = lv;
    }
}

extern "C" void kernel_launch(void* const* d_in, const int* in_sizes, int n_in,
                              void* d_out, int out_size, void* d_ws, size_t ws_size,
                              hipStream_t stream) {
    (void)in_sizes; (void)n_in; (void)out_size; (void)ws_size;
    const float* x      = (const float*)d_in[0];
    const float* w_qkv  = (const float*)d_in[1];
    const float* b_qkv  = (const float*)d_in[2];
    const float* w_proj = (const float*)d_in[3];
    const float* b_proj = (const float*)d_in[4];
    const float* rel_h  = (const float*)d_in[5];
    const float* rel_w  = (const float*)d_in[6];
    float* out = (float*)d_out;

    char* base = (char*)d_ws;
    unsigned short* xhi    = (unsigned short*)(base + 0);
    unsigned short* xlo    = (unsigned short*)(base + 12582912);
    unsigned short* wqh    = (unsigned short*)(base + 25165824);
    unsigned short* wql    = (unsigned short*)(base + 28704768);
    unsigned short* wph    = (unsigned short*)(base + 32243712);
    unsigned short* wpl    = (unsigned short*)(base + 33423360);
    unsigned short* qhi    = (unsigned short*)(base + 34603008);
    unsigned short* relcat = (unsigned short*)(base + 47185920);
    unsigned short* khi    = (unsigned short*)(base + 59768832);
    unsigned short* vT     = (unsigned short*)(base + 84934656);
    unsigned short* G      = (unsigned short*)(base + 110100480);
    unsigned short* ohif   = xhi;
    unsigned short* olo    = xlo;

    // 1. fused prep
    prep_kernel<<<8456, 256, 0, stream>>>(x, w_qkv, w_proj, rel_h, rel_w,
                                          xhi, wqh, wql, wph, wpl, relcat);
    // 2. QKV GEMM (q/k row-major, V transposed)
    qkvgemm_kernel<<<1152, 256, 0, stream>>>(xhi, wqh, b_qkv, qhi, khi, vT);
    // 3. G = q @ relcat^T
    {
        dim3 grid(8, 96);
        relgemm_kernel<<<grid, 256, 0, stream>>>(qhi, relcat, G);
    }
    // 4. attention (pre-transposed V, straight-copy staging)
    {
        dim3 grid(96, SEQ / 64);
        attn12_kernel<<<grid, 256, 0, stream>>>(qhi, khi, vT, G, ohif, olo);
    }
    // 5. proj GEMM
    projgemm_kernel<<<384, 256, 0, stream>>>(ohif, olo, wph, wpl, b_proj, out);
}